// Round 20
// baseline (345.909 us; speedup 1.0000x reference)
//
#include <hip/hip_runtime.h>
#include <math.h>

#define BATCH 256
#define D0 256
#define D1 512
#define D2 256
#define D3 128

// fp32 inter-layer activations — replicating numpy's fp32 pipeline.
__device__ float g_xnT0[D0 * BATCH];
__device__ float g_xnT1[D1 * BATCH];
__device__ float g_xnT2[D2 * BATCH];

template <int L> __device__ __forceinline__ float* xnT_ptr() {
    if constexpr (L == 0) return g_xnT0;
    else if constexpr (L == 1) return g_xnT1;
    else return g_xnT2;
}

__device__ __forceinline__ float tanh_f32_cr(float x) {
    return (float)tanh((double)x);
}

__global__ void prep_tanhT(const float* __restrict__ x) {
    int i = threadIdx.x;   // 0..255
    int b = blockIdx.x;    // 0..255
    g_xnT0[i * BATCH + b] = tanh_f32_cr(x[b * D0 + i]);
}

// Numerics (FROZEN — r17 proved it): per-term fp32 ops d=|xn-g|, m=d*s;
// RN32(exp(m)) via fp64 deg-8 Taylor + exact ldexpf (deg-7 flipped the bf16
// argmax by one quantum -> fail). Accumulation = numpy einsum baseline-SSE
// exactly: 4 lanes, unfused mul+add, reversed chain
// acc = p0+(p4+(p8+(p12+acc))), hadd tree (v0+v1)+(v2+v3). 1.95e-2 vs 2e-2.
//
// PERF history: r13 s_load path + wave=SSE-lane (4x TLP); r14 sched_barrier
// stage fences; r15 LU-templating (no LDS spill); r16 occupancy 2x (VALUBusy
// 88%, dur flat); r17 cheaper exp FAIL; r18/r19 identical-binary flake probe
// (r18 post-timing flake, r19 clean 306us). r20: cross-superblock PREFETCH of
// the 16 xn VMEM loads — issue block k+1's loads before computing block k so
// the ~200cyc L2-hit drain overlaps the ~1200cyc fenced compute. Pure-read
// prefetch, no fp op/order change -> output bit-identical by construction.
template <int IN, int LU>
__device__ __forceinline__ float sse_chain(const float* __restrict__ xnT,
                                           const float* __restrict__ wr,
                                           const float* __restrict__ sr,
                                           const int b)
{
#pragma clang fp contract(off)
    constexpr int K = IN * 5;
    float acc = 0.f;

    // ---- preload superblock 0's activations ----
    float xnv[16];
#pragma unroll
    for (int ii = 0; ii < 16; ++ii)
        xnv[ii] = xnT[ii * BATCH + b];                 // coalesced VMEM

#pragma unroll 1
    for (int blk = 0; blk < K; blk += 80) {        // 80 = lcm(16,5)
        const int ibase = blk / 5;
        // ---- prefetch NEXT superblock's activations (latency hidden by
        //      this superblock's fenced compute; waitcnt lands at the copy) ----
        float xnvn[16];
        if (blk + 80 < K) {
            const int inext = ibase + 16;
#pragma unroll
            for (int ii = 0; ii < 16; ++ii)
                xnvn[ii] = xnT[(inext + ii) * BATCH + b];
        }
        // ---- current superblock's uniform operands (scalar path) ----
        float svv[16];
#pragma unroll
        for (int ii = 0; ii < 16; ++ii)
            svv[ii] = sr[ibase + ii];                  // uniform s_load
        float wvv[20];
#pragma unroll
        for (int jj = 0; jj < 20; ++jj)
            wvv[jj] = wr[blk + 4 * jj + LU];           // uniform s_load
        __builtin_amdgcn_sched_barrier(0);

#pragma unroll
        for (int q = 0; q < 5; ++q) {              // five 16-element SSE groups
            double uu[4], pp[4];
            int ni[4];
            // ---- args + range reduction, 4 chains (ops identical to r8) ----
#pragma unroll
            for (int j = 0; j < 4; ++j) {
                constexpr int Uq[4] = {0, 4, 8, 12};
                const int U = q * 16 + Uq[j];      // compile-time
                const int c = U % 5;               // compile-time
                const int sum = c + LU;            // compile-time
                const int carry = (sum >= 5) ? 1 : 0;
                const int idx = U / 5 + carry;     // compile-time
                const float gv = 0.5f * (float)(sum - 5 * carry) - 1.0f;
                const float d = fabsf(xnv[idx] - gv);       // RN32
                const float m = -(d * svv[idx]);            // RN32
                const double tt = (double)m * 1.4426950408889634;
                const double nn = rint(tt);
                ni[j] = (int)nn;
                uu[j] = (tt - nn) * 0.6931471805599453;
            }
            __builtin_amdgcn_sched_barrier(0);
            // ---- pinned 4-wide fp64 Taylor stages (deg-8, FROZEN) ----
#pragma unroll
            for (int j = 0; j < 4; ++j) pp[j] = fma(1.0 / 40320.0, uu[j], 1.0 / 5040.0);
            __builtin_amdgcn_sched_barrier(0);
#pragma unroll
            for (int j = 0; j < 4; ++j) pp[j] = fma(pp[j], uu[j], 1.0 / 720.0);
            __builtin_amdgcn_sched_barrier(0);
#pragma unroll
            for (int j = 0; j < 4; ++j) pp[j] = fma(pp[j], uu[j], 1.0 / 120.0);
            __builtin_amdgcn_sched_barrier(0);
#pragma unroll
            for (int j = 0; j < 4; ++j) pp[j] = fma(pp[j], uu[j], 1.0 / 24.0);
            __builtin_amdgcn_sched_barrier(0);
#pragma unroll
            for (int j = 0; j < 4; ++j) pp[j] = fma(pp[j], uu[j], 1.0 / 6.0);
            __builtin_amdgcn_sched_barrier(0);
#pragma unroll
            for (int j = 0; j < 4; ++j) pp[j] = fma(pp[j], uu[j], 0.5);
            __builtin_amdgcn_sched_barrier(0);
#pragma unroll
            for (int j = 0; j < 4; ++j) pp[j] = fma(pp[j], uu[j], 1.0);
            __builtin_amdgcn_sched_barrier(0);
#pragma unroll
            for (int j = 0; j < 4; ++j) pp[j] = fma(pp[j], uu[j], 1.0);
            __builtin_amdgcn_sched_barrier(0);
            // ---- RN32 + exact 2^n + RN32 product ----
            float p[4];
#pragma unroll
            for (int j = 0; j < 4; ++j)
                p[j] = ldexpf((float)pp[j], ni[j]) * wvv[q * 4 + j];
            __builtin_amdgcn_sched_barrier(0);
            // ---- reversed chain, order-locked (j=3,2,1,0) ----
            acc = p[3] + acc;
            acc = p[2] + acc;
            acc = p[1] + acc;
            acc = p[0] + acc;
        }
        // ---- rotate prefetched operands in (last iteration: dead) ----
        if (blk + 80 < K) {
#pragma unroll
            for (int ii = 0; ii < 16; ++ii)
                xnv[ii] = xnvn[ii];
        }
    }
    return acc;
}

template <int L, int IN, int OUT, bool FINAL>
__global__ __launch_bounds__(256, 8) void kan_layer(
    const float* __restrict__ w, const float* __restrict__ s,
    const float* __restrict__ bias, float* __restrict__ outf)
{
    const int o = blockIdx.x;
    const int tid = threadIdx.x;
    const int lane = tid & 63;
    // This wave's SSE lane (0..3); readfirstlane keeps it on the scalar path.
    const int lu = __builtin_amdgcn_readfirstlane(tid >> 6);
    const int b = blockIdx.y * 64 + lane;
    const float* __restrict__ xnT = xnT_ptr<L>();
    const float* __restrict__ wr = w + (size_t)o * IN * 5;
    const float* __restrict__ sr = s + (size_t)o * IN;

    float acc;
    switch (lu) {                                  // wave-uniform scalar branch
        case 0:  acc = sse_chain<IN, 0>(xnT, wr, sr, b); break;
        case 1:  acc = sse_chain<IN, 1>(xnT, wr, sr, b); break;
        case 2:  acc = sse_chain<IN, 2>(xnT, wr, sr, b); break;
        default: acc = sse_chain<IN, 3>(xnT, wr, sr, b); break;
    }

    // Combine the 4 SSE-lane chains with the exact npyv_sum_f32 hadd
    // pairings: (v0+v1)+(v2+v3).
    __shared__ float lds[4 * 64];
    lds[lu * 64 + lane] = acc;
    __syncthreads();
    if (tid < 64) {
        const float v0 = lds[tid];
        const float v1 = lds[64 + tid];
        const float v2 = lds[128 + tid];
        const float v3 = lds[192 + tid];
        float h = (v0 + v1) + (v2 + v3);
        h = h + bias[o];                           // b == 0, exact
        const int bb = blockIdx.y * 64 + tid;
        if constexpr (FINAL) {
            outf[bb * OUT + o] = tanh_f32_cr(h);
        } else {
            xnT_ptr<L + 1>()[o * BATCH + bb] = tanh_f32_cr(fmaxf(h, 0.0f));
        }
    }
}

extern "C" void kernel_launch(void* const* d_in, const int* in_sizes, int n_in,
                              void* d_out, int out_size, void* d_ws, size_t ws_size,
                              hipStream_t stream)
{
    const float* x  = (const float*)d_in[0];
    const float* w0 = (const float*)d_in[1];
    const float* s0 = (const float*)d_in[2];
    const float* b0 = (const float*)d_in[3];
    const float* w1 = (const float*)d_in[5];
    const float* s1 = (const float*)d_in[6];
    const float* b1 = (const float*)d_in[7];
    const float* w2 = (const float*)d_in[9];
    const float* s2 = (const float*)d_in[10];
    const float* b2 = (const float*)d_in[11];
    float* out = (float*)d_out;

    prep_tanhT<<<dim3(BATCH), dim3(D0), 0, stream>>>(x);

    // 256-thread blocks = 4 waves; wave = SSE lane, lane = batch element.
    kan_layer<0, D0, D1, false><<<dim3(D1, BATCH / 64), dim3(256), 0, stream>>>(w0, s0, b0, nullptr);
    kan_layer<1, D1, D2, false><<<dim3(D2, BATCH / 64), dim3(256), 0, stream>>>(w1, s1, b1, nullptr);
    kan_layer<2, D2, D3, true ><<<dim3(D3, BATCH / 64), dim3(256), 0, stream>>>(w2, s2, b2, out);
}

// Round 21
// 305.378 us; speedup vs baseline: 1.1327x; 1.1327x over previous
//
#include <hip/hip_runtime.h>
#include <math.h>

#define BATCH 256
#define D0 256
#define D1 512
#define D2 256
#define D3 128

// fp32 inter-layer activations — replicating numpy's fp32 pipeline.
__device__ float g_xnT0[D0 * BATCH];
__device__ float g_xnT1[D1 * BATCH];
__device__ float g_xnT2[D2 * BATCH];

template <int L> __device__ __forceinline__ float* xnT_ptr() {
    if constexpr (L == 0) return g_xnT0;
    else if constexpr (L == 1) return g_xnT1;
    else return g_xnT2;
}

__device__ __forceinline__ float tanh_f32_cr(float x) {
    return (float)tanh((double)x);
}

__global__ void prep_tanhT(const float* __restrict__ x) {
    int i = threadIdx.x;   // 0..255
    int b = blockIdx.x;    // 0..255
    g_xnT0[i * BATCH + b] = tanh_f32_cr(x[b * D0 + i]);
}

// Numerics (FROZEN — r17 proved it): per-term fp32 ops d=|xn-g|, m=d*s;
// RN32(exp(m)) via fp64 deg-8 Taylor + exact ldexpf (deg-7 flipped the bf16
// argmax by one quantum -> fail). Accumulation = numpy einsum baseline-SSE
// exactly: 4 lanes, unfused mul+add, reversed chain
// acc = p0+(p4+(p8+(p12+acc))), hadd tree (v0+v1)+(v2+v3). 1.95e-2 vs 2e-2.
//
// FINAL (r21 = r19 verbatim, the banked optimum: 306us, VALUBusy 84%).
// Falsification ledger: r14/r15 schedule pinning + LU-templating (WIN,
// banked); r16 2x occupancy (neutral — issue-bound); r17 cheaper exp (FAIL
// numerics); r7/r12 accumulation restructure (FAIL numerics); r20 VMEM
// prefetch (regression — scratch spill inside the fenced region, WRITE_SIZE
// 256KB->26MB). r10/r18 were system-level flakes (identical binary passed
// on rerun). This instruction stream is mandated bit-for-bit by the
// numpy-fidelity requirement; ~85% VALU issue occupancy is its ceiling.
template <int IN, int LU>
__device__ __forceinline__ float sse_chain(const float* __restrict__ xnT,
                                           const float* __restrict__ wr,
                                           const float* __restrict__ sr,
                                           const int b)
{
#pragma clang fp contract(off)
    constexpr int K = IN * 5;
    float acc = 0.f;

#pragma unroll 1
    for (int blk = 0; blk < K; blk += 80) {        // 80 = lcm(16,5)
        const int ibase = blk / 5;
        // ---- hoisted operands: compute region below is memory-free ----
        float xnv[16], svv[16];
#pragma unroll
        for (int ii = 0; ii < 16; ++ii) {
            xnv[ii] = xnT[(ibase + ii) * BATCH + b];   // coalesced VMEM
            svv[ii] = sr[ibase + ii];                  // uniform s_load
        }
        float wvv[20];
#pragma unroll
        for (int jj = 0; jj < 20; ++jj)
            wvv[jj] = wr[blk + 4 * jj + LU];           // uniform s_load
        __builtin_amdgcn_sched_barrier(0);

#pragma unroll
        for (int q = 0; q < 5; ++q) {              // five 16-element SSE groups
            double uu[4], pp[4];
            int ni[4];
            // ---- args + range reduction, 4 chains (ops identical to r8) ----
#pragma unroll
            for (int j = 0; j < 4; ++j) {
                constexpr int Uq[4] = {0, 4, 8, 12};
                const int U = q * 16 + Uq[j];      // compile-time
                const int c = U % 5;               // compile-time
                const int sum = c + LU;            // compile-time
                const int carry = (sum >= 5) ? 1 : 0;
                const int idx = U / 5 + carry;     // compile-time
                const float gv = 0.5f * (float)(sum - 5 * carry) - 1.0f;
                const float d = fabsf(xnv[idx] - gv);       // RN32
                const float m = -(d * svv[idx]);            // RN32
                const double tt = (double)m * 1.4426950408889634;
                const double nn = rint(tt);
                ni[j] = (int)nn;
                uu[j] = (tt - nn) * 0.6931471805599453;
            }
            __builtin_amdgcn_sched_barrier(0);
            // ---- pinned 4-wide fp64 Taylor stages (deg-8, FROZEN) ----
#pragma unroll
            for (int j = 0; j < 4; ++j) pp[j] = fma(1.0 / 40320.0, uu[j], 1.0 / 5040.0);
            __builtin_amdgcn_sched_barrier(0);
#pragma unroll
            for (int j = 0; j < 4; ++j) pp[j] = fma(pp[j], uu[j], 1.0 / 720.0);
            __builtin_amdgcn_sched_barrier(0);
#pragma unroll
            for (int j = 0; j < 4; ++j) pp[j] = fma(pp[j], uu[j], 1.0 / 120.0);
            __builtin_amdgcn_sched_barrier(0);
#pragma unroll
            for (int j = 0; j < 4; ++j) pp[j] = fma(pp[j], uu[j], 1.0 / 24.0);
            __builtin_amdgcn_sched_barrier(0);
#pragma unroll
            for (int j = 0; j < 4; ++j) pp[j] = fma(pp[j], uu[j], 1.0 / 6.0);
            __builtin_amdgcn_sched_barrier(0);
#pragma unroll
            for (int j = 0; j < 4; ++j) pp[j] = fma(pp[j], uu[j], 0.5);
            __builtin_amdgcn_sched_barrier(0);
#pragma unroll
            for (int j = 0; j < 4; ++j) pp[j] = fma(pp[j], uu[j], 1.0);
            __builtin_amdgcn_sched_barrier(0);
#pragma unroll
            for (int j = 0; j < 4; ++j) pp[j] = fma(pp[j], uu[j], 1.0);
            __builtin_amdgcn_sched_barrier(0);
            // ---- RN32 + exact 2^n + RN32 product ----
            float p[4];
#pragma unroll
            for (int j = 0; j < 4; ++j)
                p[j] = ldexpf((float)pp[j], ni[j]) * wvv[q * 4 + j];
            __builtin_amdgcn_sched_barrier(0);
            // ---- reversed chain, order-locked (j=3,2,1,0) ----
            acc = p[3] + acc;
            acc = p[2] + acc;
            acc = p[1] + acc;
            acc = p[0] + acc;
        }
    }
    return acc;
}

template <int L, int IN, int OUT, bool FINAL>
__global__ __launch_bounds__(256, 8) void kan_layer(
    const float* __restrict__ w, const float* __restrict__ s,
    const float* __restrict__ bias, float* __restrict__ outf)
{
    const int o = blockIdx.x;
    const int tid = threadIdx.x;
    const int lane = tid & 63;
    // This wave's SSE lane (0..3); readfirstlane keeps it on the scalar path.
    const int lu = __builtin_amdgcn_readfirstlane(tid >> 6);
    const int b = blockIdx.y * 64 + lane;
    const float* __restrict__ xnT = xnT_ptr<L>();
    const float* __restrict__ wr = w + (size_t)o * IN * 5;
    const float* __restrict__ sr = s + (size_t)o * IN;

    float acc;
    switch (lu) {                                  // wave-uniform scalar branch
        case 0:  acc = sse_chain<IN, 0>(xnT, wr, sr, b); break;
        case 1:  acc = sse_chain<IN, 1>(xnT, wr, sr, b); break;
        case 2:  acc = sse_chain<IN, 2>(xnT, wr, sr, b); break;
        default: acc = sse_chain<IN, 3>(xnT, wr, sr, b); break;
    }

    // Combine the 4 SSE-lane chains with the exact npyv_sum_f32 hadd
    // pairings: (v0+v1)+(v2+v3).
    __shared__ float lds[4 * 64];
    lds[lu * 64 + lane] = acc;
    __syncthreads();
    if (tid < 64) {
        const float v0 = lds[tid];
        const float v1 = lds[64 + tid];
        const float v2 = lds[128 + tid];
        const float v3 = lds[192 + tid];
        float h = (v0 + v1) + (v2 + v3);
        h = h + bias[o];                           // b == 0, exact
        const int bb = blockIdx.y * 64 + tid;
        if constexpr (FINAL) {
            outf[bb * OUT + o] = tanh_f32_cr(h);
        } else {
            xnT_ptr<L + 1>()[o * BATCH + bb] = tanh_f32_cr(fmaxf(h, 0.0f));
        }
    }
}

extern "C" void kernel_launch(void* const* d_in, const int* in_sizes, int n_in,
                              void* d_out, int out_size, void* d_ws, size_t ws_size,
                              hipStream_t stream)
{
    const float* x  = (const float*)d_in[0];
    const float* w0 = (const float*)d_in[1];
    const float* s0 = (const float*)d_in[2];
    const float* b0 = (const float*)d_in[3];
    const float* w1 = (const float*)d_in[5];
    const float* s1 = (const float*)d_in[6];
    const float* b1 = (const float*)d_in[7];
    const float* w2 = (const float*)d_in[9];
    const float* s2 = (const float*)d_in[10];
    const float* b2 = (const float*)d_in[11];
    float* out = (float*)d_out;

    prep_tanhT<<<dim3(BATCH), dim3(D0), 0, stream>>>(x);

    // 256-thread blocks = 4 waves; wave = SSE lane, lane = batch element.
    kan_layer<0, D0, D1, false><<<dim3(D1, BATCH / 64), dim3(256), 0, stream>>>(w0, s0, b0, nullptr);
    kan_layer<1, D1, D2, false><<<dim3(D2, BATCH / 64), dim3(256), 0, stream>>>(w1, s1, b1, nullptr);
    kan_layer<2, D2, D3, true ><<<dim3(D3, BATCH / 64), dim3(256), 0, stream>>>(w2, s2, b2, out);
}